// Round 1
// baseline (546.108 us; speedup 1.0000x reference)
//
#include <hip/hip_runtime.h>
#include <hip/hip_bf16.h>
#include <math.h>

// Problem constants: N=4, C=256, H=W=32, NH=2, HD=128, MAX_DIS=7, WS=15, WW=225
// T = sqrt(128). Output: [hw=1024, n=4, c=256] fp32.

__device__ __forceinline__ int iclamp(int v, int lo, int hi) {
    return v < lo ? lo : (v > hi ? hi : v);
}

// ---------------------------------------------------------------------------
// Generic tiled fp32 GEMM: Y[b][d][m] = sum_c W[d][c] * X[b][c][m] (+bias[d])
// BM=BN=64, BK=16, 256 threads, 4x4 register tile.
// flags: 1 = accumulate into Y, 2 = interleaved output store
//        (Y[(col)*yStride + b*M + row], used for the final [hw][n][c] layout)
// ---------------------------------------------------------------------------
__global__ __launch_bounds__(256)
void gemm_kernel(const float* __restrict__ W, const float* __restrict__ X,
                 const float* __restrict__ bias, float* __restrict__ Y,
                 int M, int K, int N,
                 long wStride, int wMod,
                 long xStride, long yStride,
                 int biasStride, int biasMod,
                 int flags)
{
    __shared__ __align__(16) float sm[64 * 68];   // 17.4 KB, unioned
    float* Ws = sm;                // [16][68]  (k-major, d contiguous)
    float* Xs = sm + 16 * 68;      // [16][64]  (k-major, m contiguous)

    const int b = blockIdx.z;
    const float* Wb = W + (long)(b % wMod) * wStride;
    const float* Xb = X + (long)b * xStride;
    const float* biasb = bias ? (bias + (long)(b % biasMod) * biasStride) : nullptr;

    const int row0 = blockIdx.y * 64;
    const int col0 = blockIdx.x * 64;
    const int tid = threadIdx.x;
    const int tx = tid & 15, ty = tid >> 4;

    float acc[4][4];
#pragma unroll
    for (int i = 0; i < 4; ++i)
#pragma unroll
        for (int j = 0; j < 4; ++j) acc[i][j] = 0.f;

    const int ktiles = (K + 15) / 16;
    for (int kt = 0; kt < ktiles; ++kt) {
        const int c0 = kt * 16;
        // load W tile (64 d x 16 c), store transposed Ws[c][d]
#pragma unroll
        for (int i = 0; i < 4; ++i) {
            int e = tid + i * 256;
            int cc = e & 15, dd = e >> 4;
            int gd = row0 + dd, gc = c0 + cc;
            float v = 0.f;
            if (gd < M && gc < K) v = Wb[(long)gd * K + gc];
            Ws[cc * 68 + dd] = v;
        }
        // load X tile (16 c x 64 m)
#pragma unroll
        for (int i = 0; i < 4; ++i) {
            int e = tid + i * 256;
            int mm = e & 63, cc = e >> 6;
            int gc = c0 + cc;
            float v = 0.f;
            if (gc < K) v = Xb[(long)gc * N + col0 + mm];
            Xs[cc * 64 + mm] = v;
        }
        __syncthreads();
#pragma unroll
        for (int k = 0; k < 16; ++k) {
            const float4 a4 = *(const float4*)&Ws[k * 68 + ty * 4];
            const float4 b4 = *(const float4*)&Xs[k * 64 + tx * 4];
            float av[4] = {a4.x, a4.y, a4.z, a4.w};
            float bv[4] = {b4.x, b4.y, b4.z, b4.w};
#pragma unroll
            for (int i = 0; i < 4; ++i)
#pragma unroll
                for (int j = 0; j < 4; ++j) acc[i][j] += av[i] * bv[j];
        }
        __syncthreads();
    }

    if (!(flags & 2)) {
#pragma unroll
        for (int i = 0; i < 4; ++i) {
            int gd = row0 + ty * 4 + i;
            if (gd >= M) continue;
            float bvv = biasb ? biasb[gd] : 0.f;
            long yoff = (long)b * yStride + (long)gd * N + col0 + tx * 4;
            float4 r;
            r.x = acc[i][0] + bvv; r.y = acc[i][1] + bvv;
            r.z = acc[i][2] + bvv; r.w = acc[i][3] + bvv;
            if (flags & 1) {
                float4 old = *(const float4*)&Y[yoff];
                r.x += old.x; r.y += old.y; r.z += old.z; r.w += old.w;
            }
            *(float4*)&Y[yoff] = r;
        }
    } else {
        // interleaved store via LDS transpose: out[(col)*yStride + b*M + row]
        float* tile = sm;  // [64 m][68 d]
#pragma unroll
        for (int i = 0; i < 4; ++i) {
            float bvv = biasb ? biasb[row0 + ty * 4 + i] : 0.f;
#pragma unroll
            for (int j = 0; j < 4; ++j)
                tile[(tx * 4 + j) * 68 + ty * 4 + i] = acc[i][j] + bvv;
        }
        __syncthreads();
#pragma unroll
        for (int it = 0; it < 16; ++it) {
            int e = tid + it * 256;
            int dd = e & 63, mm = e >> 6;
            Y[(long)(col0 + mm) * yStride + (long)b * M + row0 + dd] = tile[mm * 68 + dd];
        }
    }
}

// ---------------------------------------------------------------------------
// Fused neighborhood attention: per (n, head, 4x8 pixel tile).
//  - stage q tile (scaled by 1/T) in LDS
//  - QK^T + rel + mask -> qk LDS [32][242]
//  - softmax (normalized attn written back to the rel buffer for the bias GEMM)
//  - value gather: 16 channels/thread through L1
// LDS: 16KB q + 31KB qk + 1.1KB scratch ~= 48.4 KB
// ---------------------------------------------------------------------------
__global__ __launch_bounds__(256)
void attn_kernel(const float* __restrict__ qp, const float* __restrict__ kp,
                 const float* __restrict__ vp, float* __restrict__ relattn,
                 float* __restrict__ agg)
{
    __shared__ __align__(16) float qs[128 * 32];
    __shared__ __align__(16) float qk[32 * 242];
    __shared__ float red[32 * 8];
    __shared__ float invl[32];

    const int tid = threadIdx.x;
    const int x0 = blockIdx.x * 8;
    const int y0 = blockIdx.y * 4;
    const int bz = blockIdx.z;           // n*2 + g
    const int n = bz >> 1, g = bz & 1;

    const long hoff = (long)(n * 256 + g * 128) * 1024;
    const float* qh = qp + hoff;
    const float* kh = kp + hoff;
    const float* vh = vp + hoff;
    float* relh = relattn + (long)bz * 225 * 1024;

    const float invT = 0.08838834764831845f;  // 1/sqrt(128)

    // stage q tile (scaled)
    for (int e = tid; e < 128 * 32; e += 256) {
        int c = e >> 5, px = e & 31;
        int py = px >> 3, pxx = px & 7;
        qs[c * 32 + px] = qh[(long)c * 1024 + (y0 + py) * 32 + (x0 + pxx)] * invT;
    }
    __syncthreads();

    // ---- phase A: scores ----
    // 480 tasks: 8 px-groups(4px, same row) x 4 dx-groups(4dx) x 15 dy
    for (int task = tid; task < 480; task += 256) {
        int pxg = task & 7;
        int t2 = task >> 3;
        int dxg = t2 & 3;
        int dy = t2 >> 2;        // 0..14
        int py = pxg >> 1;
        int pxx0 = (pxg & 1) * 4;
        int hy = y0 + py + dy - 7;
        int hyc = iclamp(hy, 0, 31);
        bool vy = (hy >= 0) && (hy < 32);
        int hx00 = x0 + pxx0 + dxg * 4 - 7;
        int hxc[7];
#pragma unroll
        for (int t = 0; t < 7; ++t) hxc[t] = iclamp(hx00 + t, 0, 31);

        const float* kr = kh + hyc * 32;
        float acc[16];
#pragma unroll
        for (int i = 0; i < 16; ++i) acc[i] = 0.f;

        for (int c = 0; c < 128; ++c) {
            const float4 q4 = *(const float4*)&qs[c * 32 + pxg * 4];
            float qa[4] = {q4.x, q4.y, q4.z, q4.w};
            float kv[7];
#pragma unroll
            for (int t = 0; t < 7; ++t) kv[t] = kr[hxc[t]];
            kr += 1024;
#pragma unroll
            for (int i = 0; i < 4; ++i)
#pragma unroll
                for (int j = 0; j < 4; ++j) acc[i * 4 + j] += qa[i] * kv[i + j];
        }
#pragma unroll
        for (int i = 0; i < 4; ++i) {
            int px = pxg * 4 + i;                       // == py*8 + pxx0 + i
            int m = (y0 + py) * 32 + x0 + pxx0 + i;
#pragma unroll
            for (int j = 0; j < 4; ++j) {
                int dx = dxg * 4 + j;
                int hx = hx00 + i + j;
                bool valid = vy && (dx < 15) && (hx >= 0) && (hx < 32);
                float val = -1e8f;
                if (valid) val = acc[i * 4 + j] + relh[(dy * 15 + dx) * 1024 + m];
                qk[px * 242 + dy * 16 + dx] = val;
            }
        }
    }
    __syncthreads();

    // ---- softmax over 240 padded window slots (invalid = -1e8 -> p = 0) ----
    {
        int px = tid >> 3, s = tid & 7;
        float mx = -3.0e38f;
        for (int w = s; w < 240; w += 8) mx = fmaxf(mx, qk[px * 242 + w]);
        red[px * 8 + s] = mx;
        __syncthreads();
#pragma unroll
        for (int t = 0; t < 8; ++t) mx = fmaxf(mx, red[px * 8 + t]);
        float sum = 0.f;
        for (int w = s; w < 240; w += 8) {
            float p = __expf(qk[px * 242 + w] - mx);
            qk[px * 242 + w] = p;
            sum += p;
        }
        __syncthreads();
        red[px * 8 + s] = sum;
        __syncthreads();
        float tot = 0.f;
#pragma unroll
        for (int t = 0; t < 8; ++t) tot += red[px * 8 + t];
        float inv = 1.0f / tot;
        if (s == 0) invl[px] = inv;
        // write normalized attn back into the rel buffer (input to bias GEMM)
        int m = (y0 + (px >> 3)) * 32 + x0 + (px & 7);
        for (int w = s; w < 240; w += 8) {
            int dy = w >> 4, dx = w & 15;
            if (dx < 15) relh[(dy * 15 + dx) * 1024 + m] = qk[px * 242 + w] * inv;
        }
    }
    __syncthreads();

    // ---- phase B: value gather, 16 channels per thread ----
    {
        int px = tid & 31, cg = tid >> 5;   // cg 0..7 -> c = cg*16 + jj
        int py = px >> 3, pxx = px & 7;
        const float* vb2 = vh + (long)cg * 16 * 1024;
        float acc[16];
#pragma unroll
        for (int i = 0; i < 16; ++i) acc[i] = 0.f;

        for (int dy = 0; dy < 15; ++dy) {
            int hy = y0 + py + dy - 7;
            int hyc = iclamp(hy, 0, 31);
            const float* vrow = vb2 + hyc * 32;
            const float* prow = &qk[px * 242 + dy * 16];
            for (int dx = 0; dx < 15; ++dx) {
                float p = prow[dx];
                if (p != 0.f) {
                    int hxcl = iclamp(x0 + pxx + dx - 7, 0, 31);
                    const float* vptr = vrow + hxcl;
#pragma unroll
                    for (int jj = 0; jj < 16; ++jj)
                        acc[jj] += p * vptr[(long)jj * 1024];
                }
            }
        }
        float inv = invl[px];
        int m = (y0 + py) * 32 + x0 + pxx;
#pragma unroll
        for (int jj = 0; jj < 16; ++jj)
            agg[(long)n * 262144 + (long)(g * 128 + cg * 16 + jj) * 1024 + m] = acc[jj] * inv;
    }
}

// ---------------------------------------------------------------------------
// kernel_launch: 7 dispatches on `stream`.
// ws layout (floats): qp[1048576] kp[1048576] vp[1048576]
//                     rel/attn[1843200] agg[1048576]   (~24.2 MB total)
// ---------------------------------------------------------------------------
extern "C" void kernel_launch(void* const* d_in, const int* in_sizes, int n_in,
                              void* d_out, int out_size, void* d_ws, size_t ws_size,
                              hipStream_t stream)
{
    const float* q    = (const float*)d_in[0];
    const float* k    = (const float*)d_in[1];
    const float* v    = (const float*)d_in[2];
    const float* Wq   = (const float*)d_in[3];
    const float* bq   = (const float*)d_in[4];
    const float* Wk   = (const float*)d_in[5];
    const float* bk   = (const float*)d_in[6];
    const float* Wv   = (const float*)d_in[7];
    const float* bv   = (const float*)d_in[8];
    const float* Wrel = (const float*)d_in[9];
    const float* brel = (const float*)d_in[10];
    const float* Vb   = (const float*)d_in[11];
    const float* Wfc  = (const float*)d_in[12];
    const float* bfc  = (const float*)d_in[13];
    float* out = (float*)d_out;

    float* ws  = (float*)d_ws;
    float* qp  = ws;
    float* kp  = ws + 1048576;
    float* vp  = ws + 2097152;
    float* rel = ws + 3145728;      // 8 * 225 * 1024, reused as attn
    float* agg = ws + 4988928;      // [n][256][1024]

    dim3 blk(256);

    // QKV projections: Y[n][d][m] = sum_c W[d][c] x[n][c][m] + b[d]
    gemm_kernel<<<dim3(16, 4, 4), blk, 0, stream>>>(Wq, q, bq, qp,
        256, 256, 1024, 0, 1, 262144, 262144, 0, 1, 0);
    gemm_kernel<<<dim3(16, 4, 4), blk, 0, stream>>>(Wk, k, bk, kp,
        256, 256, 1024, 0, 1, 262144, 262144, 0, 1, 0);
    gemm_kernel<<<dim3(16, 4, 4), blk, 0, stream>>>(Wv, v, bv, vp,
        256, 256, 1024, 0, 1, 262144, 262144, 0, 1, 0);

    // rel logits: rel[(n,g)][w][m] = sum_c Wrel[g][w][c] qp[n][g*128+c][m] + brel[g][w]
    gemm_kernel<<<dim3(16, 4, 8), blk, 0, stream>>>(Wrel, qp, brel, rel,
        225, 128, 1024, 28800, 2, 131072, 230400, 225, 2, 0);

    // fused attention: scores + softmax (attn -> rel buffer) + value gather -> agg
    attn_kernel<<<dim3(4, 8, 8), blk, 0, stream>>>(qp, kp, vp, rel, agg);

    // bias aggregation (accumulate): agg[(n,g)][c][m] += sum_w Vb[g][c][w] attn[(n,g)][w][m]
    gemm_kernel<<<dim3(16, 2, 8), blk, 0, stream>>>(Vb, rel, nullptr, agg,
        128, 225, 1024, 28800, 2, 230400, 131072, 0, 1, 1);

    // FC: out[m][n][d] = sum_c Wfc[d][c] agg[n][c][m] + bfc[d]  (interleaved store)
    gemm_kernel<<<dim3(16, 4, 4), blk, 0, stream>>>(Wfc, agg, bfc, out,
        256, 256, 1024, 0, 1, 262144, 1024, 0, 1, 2);
}